// Round 1
// baseline (1950.138 us; speedup 1.0000x reference)
//
#include <hip/hip_runtime.h>
#include <hip/hip_bf16.h>
#include <stdint.h>
#include <stddef.h>

// ---------------- problem dims (fixed by setup_inputs) ----------------
#define M_DIM 8192
#define K_DIM 4096
#define N_DIM 16384

#define BM 128
#define BN 128
#define BK 32

typedef __attribute__((ext_vector_type(8))) short bf16x8;  // 8 bf16 = 4 VGPRs
typedef __attribute__((ext_vector_type(4))) float f32x4;
typedef __attribute__((ext_vector_type(4))) int   i32x4;

// fp32 -> bf16, round-to-nearest-even (inputs finite)
static __device__ __forceinline__ short f2bf(float f) {
    union { float f; uint32_t u; } v; v.f = f;
    uint32_t r = v.u + 0x7FFFu + ((v.u >> 16) & 1u);
    return (short)(r >> 16);
}

// FP4 E2M1 decode: low 3 bits magnitude code, bit 3 sign.
// mag table {0,0.5,1,1.5,2,3,4,6} == (e==0 ? 0.5*m : (2+m)*0.25*2^e)
static __device__ __forceinline__ float e2m1(int v) {
    int e = (v >> 1) & 3;
    int m = v & 1;
    float mag = (e == 0) ? 0.5f * (float)m
                         : (float)(2 + m) * 0.25f * (float)(1 << e);
    return (v & 8) ? -mag : mag;
}

// async global->LDS, 16 bytes per lane; LDS dest must be wave-uniform base
static __device__ __forceinline__ void gload16(short* lds, const short* g) {
    __builtin_amdgcn_global_load_lds(
        (const __attribute__((address_space(1))) void*)g,
        (__attribute__((address_space(3))) void*)lds,
        16, 0, 0);
}

// ---------------- kernel 1: x fp32 -> bf16 ----------------
__global__ void cast_x_kernel(const float* __restrict__ x, short* __restrict__ xb) {
    size_t i = (size_t)blockIdx.x * 256 + threadIdx.x;   // one short8 per thread
    const float4* s = reinterpret_cast<const float4*>(x);
    float4 a = s[2 * i];
    float4 b = s[2 * i + 1];
    bf16x8 o;
    o[0] = f2bf(a.x); o[1] = f2bf(a.y); o[2] = f2bf(a.z); o[3] = f2bf(a.w);
    o[4] = f2bf(b.x); o[5] = f2bf(b.y); o[6] = f2bf(b.z); o[7] = f2bf(b.w);
    reinterpret_cast<bf16x8*>(xb)[i] = o;
}

// ---------------- kernel 2: dequant w_q -> bf16 [N, K] ----------------
// one thread per inner block of 16 elements (= 8 packed bytes)
__global__ void dequant_w_kernel(const int* __restrict__ wq,
                                 const float* __restrict__ wos,
                                 const float* __restrict__ wis,
                                 short* __restrict__ wb) {
    int tid = blockIdx.x * 256 + threadIdx.x;    // N*(K/16) = 4,194,304 total
    int n   = tid >> 8;                          // K/16 = 256 inner blocks per row
    int blk = tid & 255;
    float scale = wis[(n << 8) | blk] * wos[(n << 5) | (blk >> 3)];
    const i32x4* q = reinterpret_cast<const i32x4*>(wq + ((size_t)n << 11) + (blk << 3));
    i32x4 q0 = q[0], q1 = q[1];
    bf16x8 o0, o1;
#pragma unroll
    for (int j = 0; j < 4; ++j) {
        int c = q0[j];
        o0[2 * j]     = f2bf(e2m1(c & 15) * scale);         // even in-feature
        o0[2 * j + 1] = f2bf(e2m1((c >> 4) & 15) * scale);  // odd in-feature
    }
#pragma unroll
    for (int j = 0; j < 4; ++j) {
        int c = q1[j];
        o1[2 * j]     = f2bf(e2m1(c & 15) * scale);
        o1[2 * j + 1] = f2bf(e2m1((c >> 4) & 15) * scale);
    }
    bf16x8* dst = reinterpret_cast<bf16x8*>(wb) + 2 * (size_t)tid;
    dst[0] = o0;
    dst[1] = o1;
}

// ---------------- kernel 3: C[M,N] = A[M,K] * B[N,K]^T, bf16 in / fp32 out --
// m97 structure: 128x128 tile, BK=32, 4 waves (2x2), 4x4 16x16x32 frags/wave,
// global_load_lds width-16 staging, 2 barriers per K-step.
__global__ __launch_bounds__(256)
void gemm_bt_kernel(const short* __restrict__ A,
                    const short* __restrict__ B,
                    float* __restrict__ C) {
    __shared__ short As[BM * BK];   // 8 KB, row-major [128][32]
    __shared__ short Bs[BN * BK];   // 8 KB, row-major [128][32] (rows = N)

    // bijective XCD swizzle (nwg = 8192, divisible by 8)
    int bid = blockIdx.x;
    int cpx = gridDim.x >> 3;
    int wg  = (bid & 7) * cpx + (bid >> 3);
    int bm  = (wg & 63) << 7;       // m-fast within an XCD chunk
    int bn  = (wg >> 6) << 7;

    int t    = threadIdx.x;
    int lane = t & 63;
    int wave = t >> 6;
    int wm   = (wave >> 1) << 6;    // wave 64x64 sub-tile
    int wn   = (wave & 1) << 6;
    int fr   = lane & 15;
    int fq   = lane >> 4;

    // staging: thread t covers LDS bytes [t*16, t*16+16) of each 64-row issue
    int srow = t >> 2;              // 0..63
    int scol = (t & 3) << 3;        // 0,8,16,24
    const short* Ag = A + (size_t)(bm + srow) * K_DIM + scol;
    const short* Bg = B + (size_t)(bn + srow) * K_DIM + scol;

    short* AsW = As + wave * 512;   // wave-uniform LDS base (1024 B / wave / issue)
    short* BsW = Bs + wave * 512;

    f32x4 acc[4][4] = {};

    const bf16x8* Af = reinterpret_cast<const bf16x8*>(As);
    const bf16x8* Bf = reinterpret_cast<const bf16x8*>(Bs);
    int aoff[4], boff[4];
#pragma unroll
    for (int i = 0; i < 4; ++i) {
        aoff[i] = (wm + i * 16 + fr) * 4 + fq;   // bf16x8 index into As
        boff[i] = (wn + i * 16 + fr) * 4 + fq;
    }

    for (int k0 = 0; k0 < K_DIM; k0 += BK) {
        // stage A tile (2 issues of 64 rows) and B tile
        gload16(AsW,        Ag + k0);
        gload16(AsW + 2048, Ag + (size_t)64 * K_DIM + k0);
        gload16(BsW,        Bg + k0);
        gload16(BsW + 2048, Bg + (size_t)64 * K_DIM + k0);
        __syncthreads();   // drains vmcnt before barrier (compiler-emitted)

        bf16x8 a[4], b[4];
#pragma unroll
        for (int i = 0; i < 4; ++i) {
            a[i] = Af[aoff[i]];
            b[i] = Bf[boff[i]];
        }
#pragma unroll
        for (int mi = 0; mi < 4; ++mi)
#pragma unroll
            for (int ni = 0; ni < 4; ++ni)
                acc[mi][ni] = __builtin_amdgcn_mfma_f32_16x16x32_bf16(
                    a[mi], b[ni], acc[mi][ni], 0, 0, 0);
        __syncthreads();
    }

    // epilogue: C/D layout col = lane&15, row = (lane>>4)*4 + reg (m89/m91-verified)
#pragma unroll
    for (int mi = 0; mi < 4; ++mi) {
#pragma unroll
        for (int j = 0; j < 4; ++j) {
            size_t row = (size_t)(bm + wm + mi * 16 + fq * 4 + j);
            float* Crow = C + row * N_DIM + (bn + wn + fr);
#pragma unroll
            for (int ni = 0; ni < 4; ++ni)
                Crow[ni * 16] = acc[mi][ni][j];
        }
    }
}

// ---------------- launch ----------------
extern "C" void kernel_launch(void* const* d_in, const int* in_sizes, int n_in,
                              void* d_out, int out_size, void* d_ws, size_t ws_size,
                              hipStream_t stream) {
    const float* x   = (const float*)d_in[0];
    const int*   wq  = (const int*)d_in[1];
    const float* wos = (const float*)d_in[2];
    const float* wis = (const float*)d_in[3];
    // d_in[4] (w_t) unused: dequantizing packed codes is half the read traffic
    float* out = (float*)d_out;

    short* xb = (short*)d_ws;                                        // 64 MB
    short* wb = (short*)((char*)d_ws + (size_t)M_DIM * K_DIM * 2);   // 128 MB

    cast_x_kernel<<<(M_DIM * (size_t)K_DIM / 8) / 256, 256, 0, stream>>>(x, xb);
    dequant_w_kernel<<<(N_DIM * (size_t)K_DIM / 16) / 256, 256, 0, stream>>>(wq, wos, wis, wb);
    gemm_bt_kernel<<<(M_DIM / BM) * (N_DIM / BN), 256, 0, stream>>>(xb, wb, out);
}